// Round 17
// baseline (176.869 us; speedup 1.0000x reference)
//
#include <hip/hip_runtime.h>
#include <math.h>

#define BB 8
#define NN 1024
#define HH 32
#define II 192   // K * C = 3*64
#define DD 16
#define BN (BB*NN)
#define MT 16    // row tile
#define KP 128   // prop k-chunk (double-buffered)

typedef __attribute__((ext_vector_type(8))) short short8v;   // 8 bf16
typedef __attribute__((ext_vector_type(4))) float float4v;   // MFMA C/D

union Frag8 { short8v v; uint2 u[2]; };

// fp32 -> bf16 round-to-nearest-even (finite inputs)
static __device__ inline ushort bf(float x) {
  union { float f; unsigned u; } c; c.f = x;
  unsigned r = c.u + 0x7FFFu + ((c.u >> 16) & 1u);
  return (ushort)(r >> 16);
}

// ---------------------------------------------------------------------------
// prep_w body: W[d][i][o] f32 -> Wt[d][o][i] bf16 (one block per (layer,d))
// ---------------------------------------------------------------------------
template <int O>
static __device__ void prep_w_body(const float* __restrict__ W,
                                   ushort* __restrict__ Wt, int d,
                                   float* lds)  // stride O+1
{
  const float* Wd = W + (size_t)d * II * O;
  ushort* Wtd = Wt + (size_t)d * O * II;
  const int tid = threadIdx.x;
  for (int f = tid; f < II * O / 4; f += 256) {
    int i = f / (O / 4);
    int o4 = (f % (O / 4)) * 4;
    float4 v = *(const float4*)(Wd + (size_t)i * O + o4);
    lds[i * (O + 1) + o4 + 0] = v.x; lds[i * (O + 1) + o4 + 1] = v.y;
    lds[i * (O + 1) + o4 + 2] = v.z; lds[i * (O + 1) + o4 + 3] = v.w;
  }
  __syncthreads();
  for (int h = tid; h < II * O / 2; h += 256) {
    int o = h / (II / 2);
    int i2 = (h % (II / 2)) * 2;
    unsigned p = (unsigned)bf(lds[i2 * (O + 1) + o]) |
                 ((unsigned)bf(lds[(i2 + 1) * (O + 1) + o]) << 16);
    *(unsigned*)(Wtd + (size_t)o * II + i2) = p;
  }
}

// ---------------------------------------------------------------------------
// prep_all: [0,1024) S->bf16 | [1024,1056) w64 | [1056,1088) w32
//           [1088,1472) transposes: X[BN,32] f32 -> xbT rows [32][BN] bf16
// ---------------------------------------------------------------------------
__global__ __launch_bounds__(256) void prep_all(
    const float* __restrict__ S, ushort* __restrict__ Sb,
    const float* __restrict__ gw0, const float* __restrict__ gw1,
    ushort* __restrict__ wtg0, ushort* __restrict__ wtg1,
    const float* __restrict__ uw0, const float* __restrict__ uw1,
    ushort* __restrict__ wtu0, ushort* __restrict__ wtu1,
    const float* __restrict__ xt, const float* __restrict__ st0,
    const float* __restrict__ st1,
    ushort* __restrict__ xbTg0, ushort* __restrict__ xbTu0,
    ushort* __restrict__ xbTg1)
{
  __shared__ float ldsf[II * 65];   // 49.9 KB; reused by all branches
  int bx = blockIdx.x;
  const int tid = threadIdx.x;

  if (bx < 1024) {               // ---- S convert
    int idx = bx * 256 + tid;
    float4 v = ((const float4*)S)[idx];
    ushort4 o; o.x = bf(v.x); o.y = bf(v.y); o.z = bf(v.z); o.w = bf(v.w);
    ((ushort4*)Sb)[idx] = o;
    return;
  }
  bx -= 1024;
  if (bx < 32) {                 // ---- gate weights
    prep_w_body<64>(bx >= 16 ? gw1 : gw0, bx >= 16 ? wtg1 : wtg0, bx & 15, ldsf);
    return;
  }
  bx -= 32;
  if (bx < 32) {                 // ---- upd weights
    prep_w_body<32>(bx >= 16 ? uw1 : uw0, bx >= 16 ? wtu1 : wtu0, bx & 15, ldsf);
    return;
  }
  bx -= 32;
  // ---- transposes
  const int tensor = bx >> 7, seg = bx & 127;
  const float* src = tensor == 0 ? xt : (tensor == 1 ? st0 : st1);
  ushort* T = (ushort*)ldsf;     // [32][72]
  const int n0 = seg * 64;
#pragma unroll
  for (int q = 0; q < 2; ++q) {
    int f = tid + q * 256;
    int n = f >> 3, c4 = (f & 7) * 4;
    float4 v = *(const float4*)(src + (size_t)(n0 + n) * 32 + c4);
    T[(c4 + 0) * 72 + n] = bf(v.x); T[(c4 + 1) * 72 + n] = bf(v.y);
    T[(c4 + 2) * 72 + n] = bf(v.z); T[(c4 + 3) * 72 + n] = bf(v.w);
  }
  __syncthreads();
#pragma unroll
  for (int q = 0; q < 2; ++q) {
    int f = tid + q * 256;
    int c = f >> 4, p = f & 15;
    uint2 val = *(const uint2*)&T[c * 72 + p * 4];
    size_t off = (size_t)c * BN + n0 + p * 4;
    if (tensor == 0) {
      *(uint2*)&xbTg0[off] = val;
      *(uint2*)&xbTu0[off] = val;
    } else if (tensor == 1) {
      *(uint2*)&xbTg0[(size_t)32 * BN + off] = val;
    } else {
      *(uint2*)&xbTg1[(size_t)32 * BN + off] = val;
    }
  }
}

// ---------------------------------------------------------------------------
// S2b = bf16( 2 * Sb @ Sb )   [1024][1024], 32x32 tiles, grid (32,32)
// ---------------------------------------------------------------------------
__global__ __launch_bounds__(256) void prep_s2(
    const ushort* __restrict__ Sb, ushort* __restrict__ S2b)
{
  __shared__ ushort A[32][136];
  __shared__ ushort Bt[32][132];
  const int m0 = blockIdx.x * 32, n0 = blockIdx.y * 32;
  const int tid = threadIdx.x;
  const int w = tid >> 6, l = tid & 63;
  const int l15 = l & 15, l4 = l >> 4;
  const int wr = (w & 1) * 16, wc = (w >> 1) * 16;

  float4v acc = (float4v){0.f, 0.f, 0.f, 0.f};
  for (int k0 = 0; k0 < NN; k0 += 128) {
    __syncthreads();
#pragma unroll
    for (int q = 0; q < 2; ++q) {
      int f = tid + q * 256;
      int row = f >> 4, s8 = (f & 15) * 8;
      *(uint4*)&A[row][s8] = *(const uint4*)(Sb + (size_t)(m0 + row) * NN + k0 + s8);
    }
#pragma unroll
    for (int q = 0; q < 2; ++q) {
      int u = tid + q * 256;
      int kp = u >> 3, c4 = (u & 7) * 4;
      ushort4 a = *(const ushort4*)(Sb + (size_t)(k0 + 2 * kp) * NN + n0 + c4);
      ushort4 b = *(const ushort4*)(Sb + (size_t)(k0 + 2 * kp + 1) * NN + n0 + c4);
      *(unsigned*)&Bt[c4 + 0][2 * kp] = (unsigned)a.x | ((unsigned)b.x << 16);
      *(unsigned*)&Bt[c4 + 1][2 * kp] = (unsigned)a.y | ((unsigned)b.y << 16);
      *(unsigned*)&Bt[c4 + 2][2 * kp] = (unsigned)a.z | ((unsigned)b.z << 16);
      *(unsigned*)&Bt[c4 + 3][2 * kp] = (unsigned)a.w | ((unsigned)b.w << 16);
    }
    __syncthreads();
#pragma unroll
    for (int ks = 0; ks < 4; ++ks) {
      int kb = ks * 32 + l4 * 4;
      Frag8 af, bfr;
      af.u[0] = *(const uint2*)&A[wr + l15][kb];
      af.u[1] = *(const uint2*)&A[wr + l15][kb + 16];
      bfr.u[0] = *(const uint2*)&Bt[wc + l15][kb];
      bfr.u[1] = *(const uint2*)&Bt[wc + l15][kb + 16];
      acc = __builtin_amdgcn_mfma_f32_16x16x32_bf16(af.v, bfr.v, acc, 0, 0, 0);
    }
  }
#pragma unroll
  for (int r = 0; r < 4; ++r)
    S2b[(size_t)(m0 + wr + l4 * 4 + r) * NN + n0 + wc + l15] = bf(2.f * acc[r]);
}

// ---------------------------------------------------------------------------
// Fused graph-conv, async-split 2-phase schedule (issue-early / write-late,
// ONE barrier per round). M-tile 16, grid (NN/16, BB) = 512 blocks (2/CU).
// ---------------------------------------------------------------------------
template <int PHASE>
__global__ __launch_bounds__(256) void gconv_fused(
    const float* __restrict__ xb1,    // [BN,32] f32
    const float* __restrict__ xb2,    // [BN,32] f32 (gate: state; upd: zs)
    const ushort* __restrict__ xbT,   // [64][BN] bf16 X^T (prop staging)
    const ushort* __restrict__ Sb,    // [1024][1024] bf16
    const ushort* __restrict__ S2b,   // [1024][1024] bf16 (=2S^2)
    const float* __restrict__ emb,    // [BN,16]
    const ushort* __restrict__ Wt,    // [16][O][192] bf16
    const float* __restrict__ bias,   // [16][O]
    float* __restrict__ zr,           // PHASE0: out [BN,64]; PHASE1: in
    float* __restrict__ zs,           // PHASE0: out [BN,32]
    ushort* __restrict__ zsT,         // PHASE0: out [32][BN] bf16
    const float* __restrict__ state,  // PHASE1: [BN,32]
    float* __restrict__ hid,          // PHASE1: out [BN,32]
    float* __restrict__ outp,         // PHASE1: dup out (may be null)
    ushort* __restrict__ nxbTg,       // PHASE1 l=0: next curT (gate buf)
    ushort* __restrict__ nxbTu)      // PHASE1 l=0: next curT (upd buf)
{
  constexpr int O = PHASE == 0 ? 64 : 32;
  constexpr int NWQ = O * 24 / 256;   // uint4/thread for one W[d] tile
  union SmemU {
    struct { ushort A1[2][MT][KP + 8]; ushort A2[2][MT][KP + 8];
             ushort B[2][64][KP + 8]; } p;                       // 52.2 KB
    struct { ushort A[MT][200]; ushort B[2][O][200];
             float emb[MT][17]; float bias[16][O]; } c;          // 62.8 KB max
  };
  __shared__ SmemU sm;

  const int b = blockIdx.y;
  const int m0 = blockIdx.x * MT;
  const int tid = threadIdx.x;
  const int w = tid >> 6, l = tid & 63;
  const int l15 = l & 15, l4 = l >> 4;
  const int wcp = w * 16;

  // ---- per-thread prop staging geometry
  // A: 16 rows x 128 ushorts = 256 uint4 per matrix; tid<128 -> A1, else A2,
  //    2 uint4/thread: g = (tid&127) + q*128, row = g>>4, col = (g&15)*8.
  const int paf = tid & 127;
  const ushort* aBase = (tid < 128 ? Sb : S2b);
  const ushort* xSrcBase = xbT + (size_t)b * NN;      // + row*BN + k0 + s8

  uint4 rA[2], rB0, rB1, rB2, rB3;
#define PROP_ISSUE(k0)                                                         \
  {                                                                            \
    _Pragma("unroll")                                                          \
    for (int q = 0; q < 2; ++q) {                                              \
      int g = paf + q * 128;                                                   \
      rA[q] = *(const uint4*)(aBase + (size_t)(m0 + (g >> 4)) * NN + (k0) +    \
                              (g & 15) * 8);                                   \
    }                                                                          \
    rB0 = *(const uint4*)(xSrcBase + (size_t)((tid + 0) >> 4) * BN + (k0) + ((tid + 0) & 15) * 8); \
    rB1 = *(const uint4*)(xSrcBase + (size_t)((tid + 256) >> 4) * BN + (k0) + ((tid + 256) & 15) * 8); \
    rB2 = *(const uint4*)(xSrcBase + (size_t)((tid + 512) >> 4) * BN + (k0) + ((tid + 512) & 15) * 8); \
    rB3 = *(const uint4*)(xSrcBase + (size_t)((tid + 768) >> 4) * BN + (k0) + ((tid + 768) & 15) * 8); \
  }
#define PROP_WRITE(bq)                                                         \
  {                                                                            \
    _Pragma("unroll")                                                          \
    for (int q = 0; q < 2; ++q) {                                              \
      int g = paf + q * 128;                                                   \
      if (tid < 128) *(uint4*)&sm.p.A1[bq][g >> 4][(g & 15) * 8] = rA[q];      \
      else           *(uint4*)&sm.p.A2[bq][g >> 4][(g & 15) * 8] = rA[q];      \
    }                                                                          \
    *(uint4*)&sm.p.B[bq][(tid + 0) >> 4][((tid + 0) & 15) * 8] = rB0;          \
    *(uint4*)&sm.p.B[bq][(tid + 256) >> 4][((tid + 256) & 15) * 8] = rB1;      \
    *(uint4*)&sm.p.B[bq][(tid + 512) >> 4][((tid + 512) & 15) * 8] = rB2;      \
    *(uint4*)&sm.p.B[bq][(tid + 768) >> 4][((tid + 768) & 15) * 8] = rB3;      \
  }

  // ================= phase A: propagation =================
  float4v acc1 = (float4v){0.f, 0.f, 0.f, 0.f};
  float4v acc2 = (float4v){0.f, 0.f, 0.f, 0.f};

  PROP_ISSUE(0)
  PROP_WRITE(0)
  __syncthreads();
  int cur = 0;
  for (int k0 = 0; k0 < NN; k0 += KP) {
    if (k0 + KP < NN) PROP_ISSUE(k0 + KP)        // issue early
#pragma unroll
    for (int ks = 0; ks < KP / 32; ++ks) {       // compute current buffer
      int kb = ks * 32 + l4 * 4;
      Frag8 a1, a2, b0;
      a1.u[0] = *(const uint2*)&sm.p.A1[cur][l15][kb];
      a1.u[1] = *(const uint2*)&sm.p.A1[cur][l15][kb + 16];
      a2.u[0] = *(const uint2*)&sm.p.A2[cur][l15][kb];
      a2.u[1] = *(const uint2*)&sm.p.A2[cur][l15][kb + 16];
      b0.u[0] = *(const uint2*)&sm.p.B[cur][wcp + l15][kb];
      b0.u[1] = *(const uint2*)&sm.p.B[cur][wcp + l15][kb + 16];
      acc1 = __builtin_amdgcn_mfma_f32_16x16x32_bf16(a1.v, b0.v, acc1, 0, 0, 0);
      acc2 = __builtin_amdgcn_mfma_f32_16x16x32_bf16(a2.v, b0.v, acc2, 0, 0, 0);
    }
    if (k0 + KP < NN) PROP_WRITE(cur ^ 1)        // write late (vmcnt here)
    __syncthreads();
    cur ^= 1;
  }

  // ================= build contraction A = [X, T1, T2] =================
  {  // X cols: 16 rows x 64 cols = 256 float4 -> 1 per thread
    int row = tid >> 4, c4 = (tid & 15) * 4;
    const float* src = (c4 < 32) ? xb1 : xb2;
    float4 v = *(const float4*)(src + ((size_t)b * NN + m0 + row) * 32 + (c4 & 31));
    ushort4 o; o.x = bf(v.x); o.y = bf(v.y); o.z = bf(v.z); o.w = bf(v.w);
    *(ushort4*)&sm.c.A[row][c4] = o;
  }
#pragma unroll
  for (int r = 0; r < 4; ++r) {  // T1, T2 frags: wave w -> cols w*16
    int row = l4 * 4 + r;
    int col = wcp + l15;
    const float* src = (col < 32) ? xb1 : xb2;
    float xv = src[((size_t)b * NN + m0 + row) * 32 + (col & 31)];
    sm.c.A[row][64 + col] = bf(acc1[r]);
    sm.c.A[row][128 + col] = bf(acc2[r] - xv);
  }
  if (tid < MT * 4) {   // emb [16][16]
    int row = tid >> 2, d4 = (tid & 3) * 4;
    float4 v = *(const float4*)(emb + ((size_t)b * NN + m0 + row) * DD + d4);
    sm.c.emb[row][d4 + 0] = v.x; sm.c.emb[row][d4 + 1] = v.y;
    sm.c.emb[row][d4 + 2] = v.z; sm.c.emb[row][d4 + 3] = v.w;
  }
  for (int f = tid; f < DD * O / 4; f += 256) {   // bias [16][O]
    int d = f / (O / 4), o4 = (f % (O / 4)) * 4;
    *(float4*)&sm.c.bias[d][o4] = *(const float4*)(bias + (size_t)d * O + o4);
  }

  // ================= phase B: contraction, dbuf W, 1 barrier/round =========
  const int ocol = (PHASE == 0 ? w * 16 : (w & 1) * 16) + l15;
  const int erow = l4 * 4;

  uint4 rw[NWQ];
#define W_ISSUE(d)                                                             \
  {                                                                            \
    const ushort* Wtd = Wt + (size_t)(d) * O * II;                             \
    _Pragma("unroll")                                                          \
    for (int q = 0; q < NWQ; ++q) {                                            \
      int f = tid + q * 256;                                                   \
      rw[q] = *(const uint4*)(Wtd + (size_t)(f / 24) * II + (f % 24) * 8);     \
    }                                                                          \
  }
#define W_WRITE(bq)                                                            \
  {                                                                            \
    _Pragma("unroll")                                                          \
    for (int q = 0; q < NWQ; ++q) {                                            \
      int f = tid + q * 256;                                                   \
      *(uint4*)&sm.c.B[bq][f / 24][(f % 24) * 8] = rw[q];                      \
    }                                                                          \
  }

  float4v outacc = (float4v){0.f, 0.f, 0.f, 0.f};

  W_ISSUE(0)
  W_WRITE(0)
  __syncthreads();   // also publishes A/emb/bias builds above
  int wc2 = 0;
  for (int d = 0; d < DD; ++d) {
    if (d + 1 < DD) W_ISSUE(d + 1)               // issue early
    float4v acc = (float4v){0.f, 0.f, 0.f, 0.f};
#pragma unroll
    for (int ks = 0; ks < 6; ++ks) {
      int kb = ks * 32 + l4 * 4;
      Frag8 af, bfr;
      af.u[0] = *(const uint2*)&sm.c.A[l15][kb];
      af.u[1] = *(const uint2*)&sm.c.A[l15][kb + 16];
      bfr.u[0] = *(const uint2*)&sm.c.B[wc2][ocol][kb];
      bfr.u[1] = *(const uint2*)&sm.c.B[wc2][ocol][kb + 16];
      acc = __builtin_amdgcn_mfma_f32_16x16x32_bf16(af.v, bfr.v, acc, 0, 0, 0);
    }
    float bb = sm.c.bias[d][ocol];
    outacc[0] += sm.c.emb[erow + 0][d] * (acc[0] + bb);
    outacc[1] += sm.c.emb[erow + 1][d] * (acc[1] + bb);
    outacc[2] += sm.c.emb[erow + 2][d] * (acc[2] + bb);
    outacc[3] += sm.c.emb[erow + 3][d] * (acc[3] + bb);
    if (d + 1 < DD) {
      W_WRITE(wc2 ^ 1)                           // write late (vmcnt here)
      __syncthreads();
      wc2 ^= 1;
    }
  }
#undef PROP_ISSUE
#undef PROP_WRITE
#undef W_ISSUE
#undef W_WRITE

  // ================= fused epilogue =================
  if (PHASE == 0) {
    float zss[4];
#pragma unroll
    for (int r = 0; r < 4; ++r) {
      size_t m = (size_t)b * NN + m0 + erow + r;
      float zv = 1.f / (1.f + __expf(-outacc[r]));
      zr[m * 64 + ocol] = zv;
      if (ocol < 32) {
        float sv = zv * xb2[m * 32 + ocol];
        zs[m * 32 + ocol] = sv;
        zss[r] = sv;
      }
    }
    if (ocol < 32) {
      ushort4 pk; pk.x = bf(zss[0]); pk.y = bf(zss[1]);
      pk.z = bf(zss[2]); pk.w = bf(zss[3]);
      *(ushort4*)&zsT[(size_t)ocol * BN + (size_t)b * NN + m0 + erow] = pk;
    }
  } else if (w < 2) {
    float res[4];
#pragma unroll
    for (int r = 0; r < 4; ++r) {
      size_t m = (size_t)b * NN + m0 + erow + r;
      float hc = tanhf(outacc[r]);
      float rg = zr[m * 64 + 32 + ocol];
      float st = state[m * 32 + ocol];
      res[r] = rg * st + (1.f - rg) * hc;
      hid[m * 32 + ocol] = res[r];
      if (outp) outp[m * 32 + ocol] = res[r];
    }
    if (nxbTg) {
      ushort4 pk; pk.x = bf(res[0]); pk.y = bf(res[1]);
      pk.z = bf(res[2]); pk.w = bf(res[3]);
      size_t off = (size_t)ocol * BN + (size_t)b * NN + m0 + erow;
      *(ushort4*)&nxbTg[off] = pk;
      *(ushort4*)&nxbTu[off] = pk;
    }
  }
}

// ---------------------------------------------------------------------------
extern "C" void kernel_launch(void* const* d_in, const int* in_sizes, int n_in,
                              void* d_out, int out_size, void* d_ws, size_t ws_size,
                              hipStream_t stream)
{
  const float* xt         = (const float*)d_in[0];
  const float* init_state = (const float*)d_in[1];
  const float* S          = (const float*)d_in[2];
  const float* emb        = (const float*)d_in[3];

  float* out    = (float*)d_out;          // [BN,32] final cur
  float* hidden = out + (size_t)BN * HH;  // [2, BN, 32]

  float* zr = (float*)d_ws;                        // [BN,64]  2.0 MB
  float* zs = zr + (size_t)BN * 64;                // [BN,32]  1.0 MB
  ushort* wtg0 = (ushort*)(zs + (size_t)BN * 32);  // bf16 weights 1.5 MB
  ushort* wtu0 = wtg0 + (size_t)DD * II * 64;
  ushort* wtg1 = wtu0 + (size_t)DD * II * 32;
  ushort* wtu1 = wtg1 + (size_t)DD * II * 64;
  ushort* Sb   = wtu1 + (size_t)DD * II * 32;      // [1024][1024] bf16 2 MB
  ushort* S2b  = Sb + (size_t)NN * NN;             // [1024][1024] bf16 2 MB
  ushort* xbTg0 = S2b + (size_t)NN * NN;           // 4 x [64][BN] bf16 4 MB
  ushort* xbTu0 = xbTg0 + (size_t)64 * BN;
  ushort* xbTg1 = xbTu0 + (size_t)64 * BN;
  ushort* xbTu1 = xbTg1 + (size_t)64 * BN;

  const float* st0 = init_state;
  const float* st1 = init_state + (size_t)BN * HH;
  float* hid0 = hidden;
  float* hid1 = hidden + (size_t)BN * HH;

  prep_all<<<1472, 256, 0, stream>>>(
      S, Sb,
      (const float*)d_in[4], (const float*)d_in[8], wtg0, wtg1,
      (const float*)d_in[6], (const float*)d_in[10], wtu0, wtu1,
      xt, st0, st1, xbTg0, xbTu0, xbTg1);
  prep_s2<<<dim3(NN / 32, NN / 32), 256, 0, stream>>>(Sb, S2b);

  dim3 g(NN / MT, BB);   // 64 x 8 = 512 blocks (2/CU)
  // ---- layer 0
  gconv_fused<0><<<g, 256, 0, stream>>>(
      xt, st0, xbTg0, Sb, S2b, emb, wtg0, (const float*)d_in[5],
      zr, zs, xbTu0 + (size_t)32 * BN, nullptr, nullptr, nullptr, nullptr, nullptr);
  gconv_fused<1><<<g, 256, 0, stream>>>(
      xt, zs, xbTu0, Sb, S2b, emb, wtu0, (const float*)d_in[7],
      zr, nullptr, nullptr, st0, hid0, nullptr, xbTg1, xbTu1);
  // ---- layer 1
  gconv_fused<0><<<g, 256, 0, stream>>>(
      hid0, st1, xbTg1, Sb, S2b, emb, wtg1, (const float*)d_in[9],
      zr, zs, xbTu1 + (size_t)32 * BN, nullptr, nullptr, nullptr, nullptr, nullptr);
  gconv_fused<1><<<g, 256, 0, stream>>>(
      hid0, zs, xbTu1, Sb, S2b, emb, wtu1, (const float*)d_in[11],
      zr, nullptr, nullptr, st1, hid1, out, nullptr, nullptr);
}

// Round 18
// 134.494 us; speedup vs baseline: 1.3151x; 1.3151x over previous
//
#include <hip/hip_runtime.h>
#include <math.h>

#define BB 8
#define NN 1024
#define HH 32
#define II 192   // K * C = 3*64
#define DD 16
#define BN (BB*NN)
#define MT 16    // row tile

typedef __attribute__((ext_vector_type(8))) short short8v;   // 8 bf16
typedef __attribute__((ext_vector_type(4))) float float4v;   // MFMA C/D

union Frag8 { short8v v; uint2 u[2]; };

// fp32 -> bf16 round-to-nearest-even (finite inputs)
static __device__ inline ushort bf(float x) {
  union { float f; unsigned u; } c; c.f = x;
  unsigned r = c.u + 0x7FFFu + ((c.u >> 16) & 1u);
  return (ushort)(r >> 16);
}

// ---------------------------------------------------------------------------
// prep_w body: W[d][i][o] f32 -> Wt[d][o][i] bf16 (one block per (layer,d))
// ---------------------------------------------------------------------------
template <int O>
static __device__ void prep_w_body(const float* __restrict__ W,
                                   ushort* __restrict__ Wt, int d,
                                   float* lds)  // stride O+1
{
  const float* Wd = W + (size_t)d * II * O;
  ushort* Wtd = Wt + (size_t)d * O * II;
  const int tid = threadIdx.x;
  for (int f = tid; f < II * O / 4; f += 256) {
    int i = f / (O / 4);
    int o4 = (f % (O / 4)) * 4;
    float4 v = *(const float4*)(Wd + (size_t)i * O + o4);
    lds[i * (O + 1) + o4 + 0] = v.x; lds[i * (O + 1) + o4 + 1] = v.y;
    lds[i * (O + 1) + o4 + 2] = v.z; lds[i * (O + 1) + o4 + 3] = v.w;
  }
  __syncthreads();
  for (int h = tid; h < II * O / 2; h += 256) {
    int o = h / (II / 2);
    int i2 = (h % (II / 2)) * 2;
    unsigned p = (unsigned)bf(lds[i2 * (O + 1) + o]) |
                 ((unsigned)bf(lds[(i2 + 1) * (O + 1) + o]) << 16);
    *(unsigned*)(Wtd + (size_t)o * II + i2) = p;
  }
}

// ---------------------------------------------------------------------------
// prep_all: [0,1024) S->bf16 | [1024,1056) w64 | [1056,1088) w32
//           [1088,1472) transposes: X[BN,32] f32 -> xbT rows [32][BN] bf16
// ---------------------------------------------------------------------------
__global__ __launch_bounds__(256) void prep_all(
    const float* __restrict__ S, ushort* __restrict__ Sb,
    const float* __restrict__ gw0, const float* __restrict__ gw1,
    ushort* __restrict__ wtg0, ushort* __restrict__ wtg1,
    const float* __restrict__ uw0, const float* __restrict__ uw1,
    ushort* __restrict__ wtu0, ushort* __restrict__ wtu1,
    const float* __restrict__ xt, const float* __restrict__ st0,
    const float* __restrict__ st1,
    ushort* __restrict__ xbTg0, ushort* __restrict__ xbTu0,
    ushort* __restrict__ xbTg1)
{
  __shared__ float ldsf[II * 65];   // 49.9 KB; reused by all branches
  int bx = blockIdx.x;
  const int tid = threadIdx.x;

  if (bx < 1024) {               // ---- S convert
    int idx = bx * 256 + tid;
    float4 v = ((const float4*)S)[idx];
    ushort4 o; o.x = bf(v.x); o.y = bf(v.y); o.z = bf(v.z); o.w = bf(v.w);
    ((ushort4*)Sb)[idx] = o;
    return;
  }
  bx -= 1024;
  if (bx < 32) {                 // ---- gate weights
    prep_w_body<64>(bx >= 16 ? gw1 : gw0, bx >= 16 ? wtg1 : wtg0, bx & 15, ldsf);
    return;
  }
  bx -= 32;
  if (bx < 32) {                 // ---- upd weights
    prep_w_body<32>(bx >= 16 ? uw1 : uw0, bx >= 16 ? wtu1 : wtu0, bx & 15, ldsf);
    return;
  }
  bx -= 32;
  // ---- transposes
  const int tensor = bx >> 7, seg = bx & 127;
  const float* src = tensor == 0 ? xt : (tensor == 1 ? st0 : st1);
  ushort* T = (ushort*)ldsf;     // [32][72]
  const int n0 = seg * 64;
#pragma unroll
  for (int q = 0; q < 2; ++q) {
    int f = tid + q * 256;
    int n = f >> 3, c4 = (f & 7) * 4;
    float4 v = *(const float4*)(src + (size_t)(n0 + n) * 32 + c4);
    T[(c4 + 0) * 72 + n] = bf(v.x); T[(c4 + 1) * 72 + n] = bf(v.y);
    T[(c4 + 2) * 72 + n] = bf(v.z); T[(c4 + 3) * 72 + n] = bf(v.w);
  }
  __syncthreads();
#pragma unroll
  for (int q = 0; q < 2; ++q) {
    int f = tid + q * 256;
    int c = f >> 4, p = f & 15;
    uint2 val = *(const uint2*)&T[c * 72 + p * 4];
    size_t off = (size_t)c * BN + n0 + p * 4;
    if (tensor == 0) {
      *(uint2*)&xbTg0[off] = val;
      *(uint2*)&xbTu0[off] = val;
    } else if (tensor == 1) {
      *(uint2*)&xbTg0[(size_t)32 * BN + off] = val;
    } else {
      *(uint2*)&xbTg1[(size_t)32 * BN + off] = val;
    }
  }
}

// ---------------------------------------------------------------------------
// S2b = bf16( 2 * Sb @ Sb )   [1024][1024], 32x32 tiles, grid (32,32)
// ---------------------------------------------------------------------------
__global__ __launch_bounds__(256) void prep_s2(
    const ushort* __restrict__ Sb, ushort* __restrict__ S2b)
{
  __shared__ ushort A[32][136];
  __shared__ ushort Bt[32][132];
  const int m0 = blockIdx.x * 32, n0 = blockIdx.y * 32;
  const int tid = threadIdx.x;
  const int w = tid >> 6, l = tid & 63;
  const int l15 = l & 15, l4 = l >> 4;
  const int wr = (w & 1) * 16, wc = (w >> 1) * 16;

  float4v acc = (float4v){0.f, 0.f, 0.f, 0.f};
  for (int k0 = 0; k0 < NN; k0 += 128) {
    __syncthreads();
#pragma unroll
    for (int q = 0; q < 2; ++q) {
      int f = tid + q * 256;
      int row = f >> 4, s8 = (f & 15) * 8;
      *(uint4*)&A[row][s8] = *(const uint4*)(Sb + (size_t)(m0 + row) * NN + k0 + s8);
    }
#pragma unroll
    for (int q = 0; q < 2; ++q) {
      int u = tid + q * 256;
      int kp = u >> 3, c4 = (u & 7) * 4;
      ushort4 a = *(const ushort4*)(Sb + (size_t)(k0 + 2 * kp) * NN + n0 + c4);
      ushort4 b = *(const ushort4*)(Sb + (size_t)(k0 + 2 * kp + 1) * NN + n0 + c4);
      *(unsigned*)&Bt[c4 + 0][2 * kp] = (unsigned)a.x | ((unsigned)b.x << 16);
      *(unsigned*)&Bt[c4 + 1][2 * kp] = (unsigned)a.y | ((unsigned)b.y << 16);
      *(unsigned*)&Bt[c4 + 2][2 * kp] = (unsigned)a.z | ((unsigned)b.z << 16);
      *(unsigned*)&Bt[c4 + 3][2 * kp] = (unsigned)a.w | ((unsigned)b.w << 16);
    }
    __syncthreads();
#pragma unroll
    for (int ks = 0; ks < 4; ++ks) {
      int kb = ks * 32 + l4 * 4;
      Frag8 af, bfr;
      af.u[0] = *(const uint2*)&A[wr + l15][kb];
      af.u[1] = *(const uint2*)&A[wr + l15][kb + 16];
      bfr.u[0] = *(const uint2*)&Bt[wc + l15][kb];
      bfr.u[1] = *(const uint2*)&Bt[wc + l15][kb + 16];
      acc = __builtin_amdgcn_mfma_f32_16x16x32_bf16(af.v, bfr.v, acc, 0, 0, 0);
    }
  }
#pragma unroll
  for (int r = 0; r < 4; ++r)
    S2b[(size_t)(m0 + wr + l4 * 4 + r) * NN + n0 + wc + l15] = bf(2.f * acc[r]);
}

// ---------------------------------------------------------------------------
// Fused graph-conv (R14 schedule). M-tile 16, grid (NN/16, BB) = 512 blocks.
// PHASE 0 (gate): prop 64 cols (KC=256, 4 rounds); stores cur-half T1 (bf16)
//                 and raw T2 (f32) to gT1c/gT2c for the upd kernel.
// PHASE 1 (upd):  prop only 32 zs cols (KC=512, 2 rounds); cur-half T1/T2
//                 loaded from gT1c/gT2c (bit-identical to recompute).
// ---------------------------------------------------------------------------
template <int PHASE>
__global__ __launch_bounds__(256) void gconv_fused(
    const float* __restrict__ xb1,    // [BN,32] f32 (cur)
    const float* __restrict__ xb2,    // [BN,32] f32 (gate: state; upd: zs)
    const ushort* __restrict__ xbT,   // [64][BN] bf16 X^T (prop staging)
    const ushort* __restrict__ Sb,    // [1024][1024] bf16
    const ushort* __restrict__ S2b,   // [1024][1024] bf16 (=2S^2)
    const float* __restrict__ emb,    // [BN,16]
    const ushort* __restrict__ Wt,    // [16][O][192] bf16
    const float* __restrict__ bias,   // [16][O]
    ushort* __restrict__ gT1c,        // [BN,32] bf16: cur-half T1
    float* __restrict__ gT2c,         // [BN,32] f32 : cur-half raw T2
    float* __restrict__ zr,           // PHASE0: out [BN,64]; PHASE1: in
    float* __restrict__ zs,           // PHASE0: out [BN,32]
    ushort* __restrict__ zsT,         // PHASE0: out [32][BN] bf16
    const float* __restrict__ state,  // PHASE1: [BN,32]
    float* __restrict__ hid,          // PHASE1: out [BN,32]
    float* __restrict__ outp,         // PHASE1: dup out (may be null)
    ushort* __restrict__ nxbTg)       // PHASE1 l=0: next-layer curT (gate buf)
{
  constexpr int O   = PHASE == 0 ? 64 : 32;
  constexpr int KC  = PHASE == 0 ? 256 : 512;  // prop k-chunk
  constexpr int PB  = PHASE == 0 ? 64 : 32;    // prop B rows (X cols)
  constexpr int CPR = KC / 8;                  // uint4 per LDS row
  union SmemU {
    struct { ushort A1[MT][KC + 8]; ushort A2[MT][KC + 8];
             ushort B[PB][KC + 8]; } p;
    struct { ushort A[MT][200]; ushort B[2][O][200];
             float emb[MT][17]; float bias[16][O]; } c;
  };
  __shared__ SmemU sm;

  const int b = blockIdx.y;
  const int m0 = blockIdx.x * MT;
  const int tid = threadIdx.x;
  const int w = tid >> 6, l = tid & 63;
  const int l15 = l & 15, l4 = l >> 4;
  // prop col group: gate waves cover 64 cols; upd waves duplicate 32 cols
  const int wcp = (PHASE == 0) ? w * 16 : (w & 1) * 16;

  // ================= phase A: propagation =================
  float4v acc1 = (float4v){0.f, 0.f, 0.f, 0.f};
  float4v acc2 = (float4v){0.f, 0.f, 0.f, 0.f};
  const ushort* xSrcBase = xbT + (size_t)(PHASE == 1 ? 32 : 0) * BN + (size_t)b * NN;

  for (int k0 = 0; k0 < NN; k0 += KC) {
    __syncthreads();
    // ---- stage A1 = Sb rows, A2 = S2b rows (16 x KC each, uint4)
#pragma unroll
    for (int q = 0; q < KC / 128; ++q) {
      int f = tid + q * 256;
      int row = f / CPR, s8 = (f % CPR) * 8;
      *(uint4*)&sm.p.A1[row][s8] = *(const uint4*)(Sb + (size_t)(m0 + row) * NN + k0 + s8);
      *(uint4*)&sm.p.A2[row][s8] = *(const uint4*)(S2b + (size_t)(m0 + row) * NN + k0 + s8);
    }
    // ---- stage B = X^T rows: pure uint4 copy (PB x KC)
#pragma unroll
    for (int q = 0; q < PB * CPR / 256; ++q) {
      int f = tid + q * 256;
      int row = f / CPR, s8 = (f % CPR) * 8;
      *(uint4*)&sm.p.B[row][s8] =
          *(const uint4*)(xSrcBase + (size_t)row * BN + k0 + s8);
    }
    __syncthreads();
#pragma unroll
    for (int ks = 0; ks < KC / 32; ++ks) {
      int kb = ks * 32 + l4 * 4;
      Frag8 a1, a2, b0;
      a1.u[0] = *(const uint2*)&sm.p.A1[l15][kb];
      a1.u[1] = *(const uint2*)&sm.p.A1[l15][kb + 16];
      a2.u[0] = *(const uint2*)&sm.p.A2[l15][kb];
      a2.u[1] = *(const uint2*)&sm.p.A2[l15][kb + 16];
      b0.u[0] = *(const uint2*)&sm.p.B[wcp + l15][kb];
      b0.u[1] = *(const uint2*)&sm.p.B[wcp + l15][kb + 16];
      acc1 = __builtin_amdgcn_mfma_f32_16x16x32_bf16(a1.v, b0.v, acc1, 0, 0, 0);
      acc2 = __builtin_amdgcn_mfma_f32_16x16x32_bf16(a2.v, b0.v, acc2, 0, 0, 0);
    }
  }
  __syncthreads();   // all prop LDS reads done; union reused below

  // ---- gate: store cur-half T1/T2 for the upd kernel (waves 0,1 = cols 0..31)
  if (PHASE == 0 && w < 2) {
#pragma unroll
    for (int r = 0; r < 4; ++r) {
      size_t m = (size_t)b * NN + m0 + l4 * 4 + r;
      gT1c[m * 32 + wcp + l15] = bf(acc1[r]);
      gT2c[m * 32 + wcp + l15] = acc2[r];
    }
  }

  // ================= build contraction A = [X, T1, T2] =================
  {  // X cols: 16 rows x 64 cols = 256 float4 -> 1 per thread
    int row = tid >> 4, c4 = (tid & 15) * 4;
    const float* src = (c4 < 32) ? xb1 : xb2;
    float4 v = *(const float4*)(src + ((size_t)b * NN + m0 + row) * 32 + (c4 & 31));
    ushort4 o; o.x = bf(v.x); o.y = bf(v.y); o.z = bf(v.z); o.w = bf(v.w);
    *(ushort4*)&sm.c.A[row][c4] = o;
  }
  if (PHASE == 1) {   // cur-half T1/T2 from the gate's stores (bit-identical)
#pragma unroll
    for (int q = 0; q < 2; ++q) {
      int e = tid + q * 256;
      int row = e >> 5, c = e & 31;
      size_t m = (size_t)b * NN + m0 + row;
      sm.c.A[row][64 + c] = gT1c[m * 32 + c];
      sm.c.A[row][128 + c] = bf(gT2c[m * 32 + c] - xb1[m * 32 + c]);
    }
  }
  {  // T1, T2 frags computed here: gate cols 0..63; upd zs cols 32..63
    const int colX = (PHASE == 0 ? 0 : 32) + wcp + l15;
    if (PHASE == 0 || w < 2) {
#pragma unroll
      for (int r = 0; r < 4; ++r) {
        int row = l4 * 4 + r;
        const float* src = (colX < 32) ? xb1 : xb2;
        float xv = src[((size_t)b * NN + m0 + row) * 32 + (colX & 31)];
        sm.c.A[row][64 + colX] = bf(acc1[r]);
        sm.c.A[row][128 + colX] = bf(acc2[r] - xv);
      }
    }
  }
  if (tid < MT * 4) {   // emb [16][16]
    int row = tid >> 2, d4 = (tid & 3) * 4;
    float4 v = *(const float4*)(emb + ((size_t)b * NN + m0 + row) * DD + d4);
    sm.c.emb[row][d4 + 0] = v.x; sm.c.emb[row][d4 + 1] = v.y;
    sm.c.emb[row][d4 + 2] = v.z; sm.c.emb[row][d4 + 3] = v.w;
  }
  for (int f = tid; f < DD * O / 4; f += 256) {   // bias [16][O]
    int d = f / (O / 4), o4 = (f % (O / 4)) * 4;
    *(float4*)&sm.c.bias[d][o4] = *(const float4*)(bias + (size_t)d * O + o4);
  }

  // ================= phase B: meta contraction (2 d per stage) =============
  const int ocol = (PHASE == 0 ? w * 16 : (w & 1) * 16) + l15;
  const int erow = l4 * 4;

  float4v outacc = (float4v){0.f, 0.f, 0.f, 0.f};

  for (int d = 0; d < DD; d += 2) {
    __syncthreads();
    const ushort* Wtd = Wt + (size_t)d * O * II;
#pragma unroll
    for (int q = 0; q < 2 * O * 24 / 256; ++q) {
      int f = tid + q * 256;
      int dd = f / (O * 24), rem = f % (O * 24);
      int o = rem / 24, k8 = (rem % 24) * 8;
      *(uint4*)&sm.c.B[dd][o][k8] = *(const uint4*)(Wtd + ((size_t)dd * O + o) * II + k8);
    }
    __syncthreads();

#pragma unroll
    for (int dd = 0; dd < 2; ++dd) {
      float4v acc = (float4v){0.f, 0.f, 0.f, 0.f};
#pragma unroll
      for (int ks = 0; ks < 6; ++ks) {
        int kb = ks * 32 + l4 * 4;
        Frag8 af, bfr;
        af.u[0] = *(const uint2*)&sm.c.A[l15][kb];
        af.u[1] = *(const uint2*)&sm.c.A[l15][kb + 16];
        bfr.u[0] = *(const uint2*)&sm.c.B[dd][ocol][kb];
        bfr.u[1] = *(const uint2*)&sm.c.B[dd][ocol][kb + 16];
        acc = __builtin_amdgcn_mfma_f32_16x16x32_bf16(af.v, bfr.v, acc, 0, 0, 0);
      }
      float bb = sm.c.bias[d + dd][ocol];
      outacc[0] += sm.c.emb[erow + 0][d + dd] * (acc[0] + bb);
      outacc[1] += sm.c.emb[erow + 1][d + dd] * (acc[1] + bb);
      outacc[2] += sm.c.emb[erow + 2][d + dd] * (acc[2] + bb);
      outacc[3] += sm.c.emb[erow + 3][d + dd] * (acc[3] + bb);
    }
  }

  // ================= fused epilogue =================
  if (PHASE == 0) {
    float zss[4];
#pragma unroll
    for (int r = 0; r < 4; ++r) {
      size_t m = (size_t)b * NN + m0 + erow + r;
      float zv = 1.f / (1.f + __expf(-outacc[r]));
      zr[m * 64 + ocol] = zv;
      if (ocol < 32) {
        float sv = zv * xb2[m * 32 + ocol];
        zs[m * 32 + ocol] = sv;
        zss[r] = sv;
      }
    }
    if (ocol < 32) {
      ushort4 pk; pk.x = bf(zss[0]); pk.y = bf(zss[1]);
      pk.z = bf(zss[2]); pk.w = bf(zss[3]);
      *(ushort4*)&zsT[(size_t)ocol * BN + (size_t)b * NN + m0 + erow] = pk;
    }
  } else if (w < 2) {
    float res[4];
#pragma unroll
    for (int r = 0; r < 4; ++r) {
      size_t m = (size_t)b * NN + m0 + erow + r;
      float hc = tanhf(outacc[r]);
      float rg = zr[m * 64 + 32 + ocol];
      float st = state[m * 32 + ocol];
      res[r] = rg * st + (1.f - rg) * hc;
      hid[m * 32 + ocol] = res[r];
      if (outp) outp[m * 32 + ocol] = res[r];
    }
    if (nxbTg) {       // next layer's curT (gate buffer rows 0..31)
      ushort4 pk; pk.x = bf(res[0]); pk.y = bf(res[1]);
      pk.z = bf(res[2]); pk.w = bf(res[3]);
      *(ushort4*)&nxbTg[(size_t)ocol * BN + (size_t)b * NN + m0 + erow] = pk;
    }
  }
}

// ---------------------------------------------------------------------------
extern "C" void kernel_launch(void* const* d_in, const int* in_sizes, int n_in,
                              void* d_out, int out_size, void* d_ws, size_t ws_size,
                              hipStream_t stream)
{
  const float* xt         = (const float*)d_in[0];
  const float* init_state = (const float*)d_in[1];
  const float* S          = (const float*)d_in[2];
  const float* emb        = (const float*)d_in[3];

  float* out    = (float*)d_out;          // [BN,32] final cur
  float* hidden = out + (size_t)BN * HH;  // [2, BN, 32]

  float* zr = (float*)d_ws;                        // [BN,64]  2.0 MB
  float* zs = zr + (size_t)BN * 64;                // [BN,32]  1.0 MB
  ushort* wtg0 = (ushort*)(zs + (size_t)BN * 32);  // bf16 weights 1.5 MB
  ushort* wtu0 = wtg0 + (size_t)DD * II * 64;
  ushort* wtg1 = wtu0 + (size_t)DD * II * 32;
  ushort* wtu1 = wtg1 + (size_t)DD * II * 64;
  ushort* Sb   = wtu1 + (size_t)DD * II * 32;      // [1024][1024] bf16 2 MB
  ushort* S2b  = Sb + (size_t)NN * NN;             // [1024][1024] bf16 2 MB
  ushort* xbTg0 = S2b + (size_t)NN * NN;           // 4 x [64][BN] bf16 4 MB
  ushort* xbTu0 = xbTg0 + (size_t)64 * BN;
  ushort* xbTg1 = xbTu0 + (size_t)64 * BN;
  ushort* xbTu1 = xbTg1 + (size_t)64 * BN;
  ushort* gT1c = xbTu1 + (size_t)64 * BN;          // [BN,32] bf16 0.5 MB
  float*  gT2c = (float*)(gT1c + (size_t)32 * BN); // [BN,32] f32  1.0 MB

  const float* st0 = init_state;
  const float* st1 = init_state + (size_t)BN * HH;
  float* hid0 = hidden;
  float* hid1 = hidden + (size_t)BN * HH;

  prep_all<<<1472, 256, 0, stream>>>(
      S, Sb,
      (const float*)d_in[4], (const float*)d_in[8], wtg0, wtg1,
      (const float*)d_in[6], (const float*)d_in[10], wtu0, wtu1,
      xt, st0, st1, xbTg0, xbTu0, xbTg1);
  prep_s2<<<dim3(NN / 32, NN / 32), 256, 0, stream>>>(Sb, S2b);

  dim3 g(NN / MT, BB);   // 64 x 8 = 512 blocks (2/CU)
  // ---- layer 0
  gconv_fused<0><<<g, 256, 0, stream>>>(
      xt, st0, xbTg0, Sb, S2b, emb, wtg0, (const float*)d_in[5],
      gT1c, gT2c, zr, zs, xbTu0 + (size_t)32 * BN, nullptr, nullptr, nullptr,
      nullptr);
  gconv_fused<1><<<g, 256, 0, stream>>>(
      xt, zs, xbTu0, Sb, S2b, emb, wtu0, (const float*)d_in[7],
      gT1c, gT2c, zr, nullptr, nullptr, st0, hid0, nullptr, xbTg1);
  // ---- layer 1
  gconv_fused<0><<<g, 256, 0, stream>>>(
      hid0, st1, xbTg1, Sb, S2b, emb, wtg1, (const float*)d_in[9],
      gT1c, gT2c, zr, zs, xbTu1 + (size_t)32 * BN, nullptr, nullptr, nullptr,
      nullptr);
  gconv_fused<1><<<g, 256, 0, stream>>>(
      hid0, zs, xbTu1, Sb, S2b, emb, wtu1, (const float*)d_in[11],
      gT1c, gT2c, zr, nullptr, nullptr, st1, hid1, out, nullptr);
}